// Round 4
// baseline (1496.606 us; speedup 1.0000x reference)
//
#include <hip/hip_runtime.h>

typedef unsigned short u16;
typedef __attribute__((ext_vector_type(8))) __bf16 bf16x8;
typedef __attribute__((ext_vector_type(8))) unsigned short u16x8;
typedef __attribute__((ext_vector_type(4))) float f32x4;

__device__ __forceinline__ float bf2f(u16 u) {
  unsigned int x = ((unsigned int)u) << 16;
  return __builtin_bit_cast(float, x);
}
__device__ __forceinline__ u16 f2bf(float f) {
  unsigned int x = __builtin_bit_cast(unsigned int, f);
  x += 0x7fffu + ((x >> 16) & 1u);
  return (u16)(x >> 16);
}
// load 8 consecutive f32, round-to-nearest-even to bf16x8
__device__ __forceinline__ bf16x8 cvt8(const float* p) {
  f32x4 a = *(const f32x4*)p;
  f32x4 b = *(const f32x4*)(p + 4);
  u16x8 r;
#pragma unroll
  for (int j = 0; j < 4; ++j) { r[j] = f2bf(a[j]); r[4 + j] = f2bf(b[j]); }
  return __builtin_bit_cast(bf16x8, r);
}

// ---------------------------------------------------------------- GEMM
// C[M,N] = A[M,K] @ B[K,N].  AF32/BF32: input dtypes (f32 converted to bf16
// during staging).  OF32: output dtype.  tr==1: write C transposed [N,M].
// 128x128 tile, BK=32, register-round-trip staging; B transposed in LDS so
// fragment reads are contiguous 16B.
template <int AF32, int BF32, int OF32>
__global__ __launch_bounds__(256) void gemm(const void* __restrict__ Av,
                                            const void* __restrict__ Bv,
                                            void* __restrict__ Cv,
                                            int M, int N, int K, int tr) {
  __shared__ __align__(16) u16 As[128 * 32];  // [m][k]
  __shared__ __align__(16) u16 Bs[128 * 32];  // [n][k]
  const int tid = threadIdx.x, lane = tid & 63, w = tid >> 6;
  const int quad = lane >> 4, c16 = lane & 15;
  const int rw = lane >> 2, c4 = lane & 3;
  const int bm = blockIdx.x * 128, bn = blockIdx.y * 128;
  const int wm = (w >> 1) * 64, wn = (w & 1) * 64;
  const int kr = tid >> 4, cn = (tid & 15) * 8;  // B-staging coords

  f32x4 acc[4][4] = {};

  for (int k0 = 0; k0 < K; k0 += 32) {
    // prefetch to registers
    bf16x8 va0, va1;
    if (AF32) {
      const float* A = (const float*)Av;
      va0 = cvt8(&A[(size_t)(bm + w * 16 + rw) * K + k0 + c4 * 8]);
      va1 = cvt8(&A[(size_t)(bm + 64 + w * 16 + rw) * K + k0 + c4 * 8]);
    } else {
      const u16* A = (const u16*)Av;
      va0 = *(const bf16x8*)&A[(size_t)(bm + w * 16 + rw) * K + k0 + c4 * 8];
      va1 = *(const bf16x8*)&A[(size_t)(bm + 64 + w * 16 + rw) * K + k0 + c4 * 8];
    }
    u16 b0[8], b1[8];
    if (BF32) {
      const float* B = (const float*)Bv;
      f32x4 x0 = *(const f32x4*)&B[(size_t)(k0 + kr) * N + bn + cn];
      f32x4 x1 = *(const f32x4*)&B[(size_t)(k0 + kr) * N + bn + cn + 4];
      f32x4 y0 = *(const f32x4*)&B[(size_t)(k0 + 16 + kr) * N + bn + cn];
      f32x4 y1 = *(const f32x4*)&B[(size_t)(k0 + 16 + kr) * N + bn + cn + 4];
#pragma unroll
      for (int j = 0; j < 4; ++j) {
        b0[j] = f2bf(x0[j]); b0[4 + j] = f2bf(x1[j]);
        b1[j] = f2bf(y0[j]); b1[4 + j] = f2bf(y1[j]);
      }
    } else {
      const u16* B = (const u16*)Bv;
      u16x8 v0 = *(const u16x8*)&B[(size_t)(k0 + kr) * N + bn + cn];
      u16x8 v1 = *(const u16x8*)&B[(size_t)(k0 + 16 + kr) * N + bn + cn];
#pragma unroll
      for (int j = 0; j < 8; ++j) { b0[j] = v0[j]; b1[j] = v1[j]; }
    }
    __syncthreads();  // previous iteration's fragment reads complete
    *(bf16x8*)&As[(w * 16 + rw) * 32 + c4 * 8] = va0;
    *(bf16x8*)&As[(64 + w * 16 + rw) * 32 + c4 * 8] = va1;
#pragma unroll
    for (int j = 0; j < 8; ++j) {
      Bs[(cn + j) * 32 + kr] = b0[j];
      Bs[(cn + j) * 32 + 16 + kr] = b1[j];
    }
    __syncthreads();
    bf16x8 a[4], b[4];
#pragma unroll
    for (int mt = 0; mt < 4; ++mt)
      a[mt] = *(const bf16x8*)&As[(wm + mt * 16 + c16) * 32 + quad * 8];
#pragma unroll
    for (int nt = 0; nt < 4; ++nt)
      b[nt] = *(const bf16x8*)&Bs[(wn + nt * 16 + c16) * 32 + quad * 8];
#pragma unroll
    for (int mt = 0; mt < 4; ++mt)
#pragma unroll
      for (int nt = 0; nt < 4; ++nt)
        acc[mt][nt] = __builtin_amdgcn_mfma_f32_16x16x32_bf16(a[mt], b[nt], acc[mt][nt], 0, 0, 0);
  }
#pragma unroll
  for (int mt = 0; mt < 4; ++mt)
#pragma unroll
    for (int nt = 0; nt < 4; ++nt)
#pragma unroll
      for (int r = 0; r < 4; ++r) {
        const int row = bm + wm + mt * 16 + quad * 4 + r;
        const int col = bn + wn + nt * 16 + c16;
        const size_t idx = tr ? (size_t)col * M + row : (size_t)row * N + col;
        if (OF32)
          ((float*)Cv)[idx] = acc[mt][nt][r];
        else
          ((u16*)Cv)[idx] = f2bf(acc[mt][nt][r]);
      }
}

// ---------------------------------------------------------------- RoPE (in place, bf16)
__global__ void rope_kernel(u16* __restrict__ buf, const int* __restrict__ pos,
                            int log2nh, float oscale) {
  const int t = blockIdx.x * 256 + threadIdx.x;
  const int i = t & 63;
  const int h = (t >> 6) & ((1 << log2nh) - 1);
  const int s = t >> (6 + log2nh);
  const int nh = 1 << log2nh;
  const float p = (float)pos[s];
  const float invf = exp2f((float)i * -0.20762051915861040f);  // 10000^(-i/64)
  const float ang = p * invf;
  const float cn = cosf(ang), sn = sinf(ang);
  const size_t i1 = (size_t)s * (nh * 128) + h * 128 + i;
  const size_t i2 = i1 + 64;
  const float x1 = bf2f(buf[i1]), x2 = bf2f(buf[i2]);
  buf[i1] = f2bf((x1 * cn - x2 * sn) * oscale);
  buf[i2] = f2bf((x2 * cn + x1 * sn) * oscale);
}

// ---------------------------------------------------------------- flash attention
// Q: [S,32*128] bf16 (RoPE'd, pre-scaled 1/sqrt(128));  K: [S,8*128] bf16
// VT: [8*128, S] bf16;  O: [S,32*128] bf16.  Block = 64 q-rows x 1 head;
// wave w owns rows w*16..w*16+15.
__global__ __launch_bounds__(256) void flash_kernel(const u16* __restrict__ Q,
                                                    const u16* __restrict__ K,
                                                    const u16* __restrict__ VT,
                                                    u16* __restrict__ O) {
  __shared__ __align__(16) u16 Qs[4 * 64 * 32];    // [kc][m][32]
  __shared__ __align__(16) u16 Ks[4 * 64 * 32];    // [kc][key][32]
  __shared__ __align__(16) u16 Vts[2 * 128 * 32];  // [kc2][d][32 keys]
  __shared__ __align__(16) u16 Ps[4][16 * 72];     // per-wave P tile, 144B rows
  const int qb = blockIdx.x, h = blockIdx.y, kvh = h >> 2;
  const int tid = threadIdx.x, lane = tid & 63, w = tid >> 6;
  const int quad = lane >> 4, c16 = lane & 15;
  const int rw = lane >> 2, c4 = lane & 3;

#pragma unroll
  for (int p = 0; p < 4; ++p) {
    bf16x8 v = *(const bf16x8*)&Q[(size_t)(qb * 64 + w * 16 + rw) * 4096 + h * 128 + p * 32 + c4 * 8];
    *(bf16x8*)&Qs[(p * 64 + w * 16 + rw) * 32 + c4 * 8] = v;
  }
  __syncthreads();
  bf16x8 aq[4];
#pragma unroll
  for (int kc = 0; kc < 4; ++kc)
    aq[kc] = *(const bf16x8*)&Qs[(kc * 64 + w * 16 + c16) * 32 + quad * 8];

  f32x4 acc_o[8] = {};
  float m_run[4], l_run[4];
#pragma unroll
  for (int r = 0; r < 4; ++r) { m_run[r] = -1e30f; l_run[r] = 0.f; }

  for (int t = 0; t <= qb; ++t) {
    bf16x8 kv[4], vv[4];
#pragma unroll
    for (int p = 0; p < 4; ++p) {
      kv[p] = *(const bf16x8*)&K[(size_t)(t * 64 + w * 16 + rw) * 1024 + kvh * 128 + p * 32 + c4 * 8];
      const int d = (p & 1) * 64 + w * 16 + rw;
      vv[p] = *(const bf16x8*)&VT[(size_t)(kvh * 128 + d) * 2048 + t * 64 + (p >> 1) * 32 + c4 * 8];
    }
    __syncthreads();  // all waves done reading Ks/Vts from previous iter
#pragma unroll
    for (int p = 0; p < 4; ++p) {
      *(bf16x8*)&Ks[(p * 64 + w * 16 + rw) * 32 + c4 * 8] = kv[p];
      *(bf16x8*)&Vts[(p * 64 + w * 16 + rw) * 32 + c4 * 8] = vv[p];
    }
    __syncthreads();

    f32x4 sacc[4];
#pragma unroll
    for (int nt = 0; nt < 4; ++nt) {
      f32x4 s = {0.f, 0.f, 0.f, 0.f};
#pragma unroll
      for (int kc = 0; kc < 4; ++kc) {
        bf16x8 bk = *(const bf16x8*)&Ks[(kc * 64 + nt * 16 + c16) * 32 + quad * 8];
        s = __builtin_amdgcn_mfma_f32_16x16x32_bf16(aq[kc], bk, s, 0, 0, 0);
      }
      sacc[nt] = s;
    }
    if (t == qb) {  // causal mask on diagonal tile
#pragma unroll
      for (int nt = 0; nt < 4; ++nt)
#pragma unroll
        for (int r = 0; r < 4; ++r)
          if (nt * 16 + c16 > w * 16 + quad * 4 + r) sacc[nt][r] = -1e30f;
    }
    float al[4];
#pragma unroll
    for (int r = 0; r < 4; ++r) {
      float mx = fmaxf(fmaxf(sacc[0][r], sacc[1][r]), fmaxf(sacc[2][r], sacc[3][r]));
#pragma unroll
      for (int off = 1; off < 16; off <<= 1) mx = fmaxf(mx, __shfl_xor(mx, off));
      const float nm = fmaxf(m_run[r], mx);
      al[r] = __expf(m_run[r] - nm);
      m_run[r] = nm;
      float sum = 0.f;
#pragma unroll
      for (int nt = 0; nt < 4; ++nt) {
        const float pv = __expf(sacc[nt][r] - nm);
        sacc[nt][r] = pv;
        sum += pv;
      }
#pragma unroll
      for (int off = 1; off < 16; off <<= 1) sum += __shfl_xor(sum, off);
      l_run[r] = l_run[r] * al[r] + sum;
    }
#pragma unroll
    for (int dt = 0; dt < 8; ++dt)
#pragma unroll
      for (int r = 0; r < 4; ++r) acc_o[dt][r] *= al[r];
    // P: C-layout -> LDS -> A-layout (wave-private region; fence pins order)
#pragma unroll
    for (int nt = 0; nt < 4; ++nt)
#pragma unroll
      for (int r = 0; r < 4; ++r)
        Ps[w][(quad * 4 + r) * 72 + nt * 16 + c16] = f2bf(sacc[nt][r]);
    asm volatile("s_waitcnt lgkmcnt(0)" ::: "memory");
    bf16x8 ap[2];
#pragma unroll
    for (int kc = 0; kc < 2; ++kc)
      ap[kc] = *(const bf16x8*)&Ps[w][c16 * 72 + kc * 32 + quad * 8];
#pragma unroll
    for (int dt = 0; dt < 8; ++dt)
#pragma unroll
      for (int kc = 0; kc < 2; ++kc) {
        bf16x8 bv = *(const bf16x8*)&Vts[(kc * 128 + dt * 16 + c16) * 32 + quad * 8];
        acc_o[dt] = __builtin_amdgcn_mfma_f32_16x16x32_bf16(ap[kc], bv, acc_o[dt], 0, 0, 0);
      }
  }
#pragma unroll
  for (int r = 0; r < 4; ++r) {
    const float inv = 1.0f / l_run[r];
    const int row = qb * 64 + w * 16 + quad * 4 + r;
#pragma unroll
    for (int dt = 0; dt < 8; ++dt)
      O[(size_t)row * 4096 + h * 128 + dt * 16 + c16] = f2bf(acc_o[dt][r] * inv);
  }
}

// ---------------------------------------------------------------- launch
extern "C" void kernel_launch(void* const* d_in, const int* in_sizes, int n_in,
                              void* d_out, int out_size, void* d_ws, size_t ws_size,
                              hipStream_t stream) {
  const float* X  = (const float*)d_in[0];   // [2048, 4096] f32
  // d_in[1] attention_mask (f32) is causal-with-arange -> applied analytically
  const int* pos  = (const int*)d_in[2];
  const float* Wq = (const float*)d_in[3];   // [4096, 4096] f32
  const float* Wk = (const float*)d_in[4];   // [4096, 1024] f32
  const float* Wv = (const float*)d_in[5];   // [4096, 1024] f32
  const float* Wo = (const float*)d_in[6];   // [4096, 4096] f32
  float* out = (float*)d_out;                // [2048, 4096] f32

  // Workspace: 40 MB of bf16 intermediates.
  char* ws = (char*)d_ws;
  u16* Qb  = (u16*)(ws + 0);          // 16,777,216 B
  u16* Kb  = (u16*)(ws + 16777216);   //  4,194,304 B
  u16* VTb = (u16*)(ws + 20971520);   //  4,194,304 B  (V transposed [1024,2048])
  u16* Att = (u16*)(ws + 25165824);   // 16,777,216 B  (end 41,943,040)

  const dim3 b256(256);

  gemm<1, 1, 0><<<dim3(16, 32), b256, 0, stream>>>(X, Wq, Qb, 2048, 4096, 4096, 0);
  gemm<1, 1, 0><<<dim3(16, 8),  b256, 0, stream>>>(X, Wk, Kb, 2048, 1024, 4096, 0);
  gemm<1, 1, 0><<<dim3(16, 8),  b256, 0, stream>>>(X, Wv, VTb, 2048, 1024, 4096, 1);

  // Q pre-scaled by 1/sqrt(128) in RoPE
  rope_kernel<<<dim3(2048 * 32 * 64 / 256), b256, 0, stream>>>(Qb, pos, 5, 0.08838834764831845f);
  rope_kernel<<<dim3(2048 * 8 * 64 / 256),  b256, 0, stream>>>(Kb, pos, 3, 1.0f);

  flash_kernel<<<dim3(32, 32), b256, 0, stream>>>(Qb, Kb, VTb, Att);

  gemm<0, 1, 1><<<dim3(16, 32), b256, 0, stream>>>(Att, Wo, out, 2048, 4096, 4096, 0);
}

// Round 5
// 931.044 us; speedup vs baseline: 1.6074x; 1.6074x over previous
//
#include <hip/hip_runtime.h>

typedef unsigned short u16;
typedef __attribute__((ext_vector_type(8))) __bf16 bf16x8;
typedef __attribute__((ext_vector_type(8))) unsigned short u16x8;
typedef __attribute__((ext_vector_type(4))) float f32x4;

#define AS1 __attribute__((address_space(1)))
#define AS3 __attribute__((address_space(3)))

__device__ __forceinline__ void load_lds16(const void* g, void* l) {
  __builtin_amdgcn_global_load_lds((const AS1 unsigned int*)g,
                                   (AS3 unsigned int*)l, 16, 0, 0);
}

__device__ __forceinline__ float bf2f(u16 u) {
  unsigned int x = ((unsigned int)u) << 16;
  return __builtin_bit_cast(float, x);
}
__device__ __forceinline__ u16 f2bf(float f) {
  unsigned int x = __builtin_bit_cast(unsigned int, f);
  x += 0x7fffu + ((x >> 16) & 1u);
  return (u16)(x >> 16);
}
// load 8 consecutive f32, RNE-convert to bf16x8
__device__ __forceinline__ bf16x8 cvt8(const float* p) {
  f32x4 a = *(const f32x4*)p;
  f32x4 b = *(const f32x4*)(p + 4);
  u16x8 r;
#pragma unroll
  for (int j = 0; j < 4; ++j) { r[j] = f2bf(a[j]); r[4 + j] = f2bf(b[j]); }
  return __builtin_bit_cast(bf16x8, r);
}

// ---------------------------------------------------------------- weight transpose
// out[c - col0][r] = bf16(in[r*C + c])  for c in [col0, col0+Cpanel)
// 32x33-padded LDS tile: conflict-free.
__global__ __launch_bounds__(256) void transpose_w(const float* __restrict__ in,
                                                   u16* __restrict__ out,
                                                   int R, int C, int col0) {
  __shared__ u16 tile[32][33];
  const int tx = threadIdx.x & 31, ty = threadIdx.x >> 5;
  const int c0 = blockIdx.x * 32, r0 = blockIdx.y * 32;  // c0: panel-local col
#pragma unroll
  for (int j = ty; j < 32; j += 8)
    tile[j][tx] = f2bf(in[(size_t)(r0 + j) * C + col0 + c0 + tx]);
  __syncthreads();
#pragma unroll
  for (int j = ty; j < 32; j += 8)
    out[(size_t)(c0 + j) * R + r0 + tx] = tile[tx][j];
}

// ---------------------------------------------------------------- GEMM (m97 structure)
// C[M,N] = A[M,K] @ Bt[N,K]^T.  A: f32 (AF32=1, converted in-staging) or bf16
// (AF32=0, global_load_lds).  B: bf16 [N,K] via global_load_lds width-16.
// OF32: C dtype.  TR: write C[col*ldC + row] (transposed).  128x128 tile, BK=32.
template <int AF32, int OF32, int TR>
__global__ __launch_bounds__(256) void gemm_bt(const void* __restrict__ Av,
                                               const u16* __restrict__ Bt,
                                               void* __restrict__ Cv,
                                               int M, int N, int K, int ldC) {
  __shared__ __align__(16) u16 As[128 * 32];
  __shared__ __align__(16) u16 Bs[128 * 32];
  const int tid = threadIdx.x, lane = tid & 63, w = tid >> 6;
  const int quad = lane >> 4, c16 = lane & 15;
  const int rw = lane >> 2, c4 = lane & 3;
  const int bm = blockIdx.x * 128, bn = blockIdx.y * 128;
  const int wm = (w >> 1) * 64, wn = (w & 1) * 64;

  f32x4 acc[4][4] = {};

  const u16* Ab = (const u16*)Av;
  const float* Af = (const float*)Av;
  const u16* Ag0 = Ab + (size_t)(bm + w * 16 + rw) * K + c4 * 8;
  const u16* Ag1 = Ag0 + (size_t)64 * K;
  const float* Af0 = Af + (size_t)(bm + w * 16 + rw) * K + c4 * 8;
  const float* Af1 = Af0 + (size_t)64 * K;
  const u16* Bg0 = Bt + (size_t)(bn + w * 16 + rw) * K + c4 * 8;
  const u16* Bg1 = Bg0 + (size_t)64 * K;
  u16* As0 = &As[(w * 16) * 32];
  u16* As1 = &As[(64 + w * 16) * 32];
  u16* Bs0 = &Bs[(w * 16) * 32];
  u16* Bs1 = &Bs[(64 + w * 16) * 32];

  for (int k0 = 0; k0 < K; k0 += 32) {
    bf16x8 va0, va1;
    if (AF32) {  // register prefetch + convert (issue before DMA)
      va0 = cvt8(Af0 + k0);
      va1 = cvt8(Af1 + k0);
    } else {
      load_lds16(Ag0 + k0, As0);
      load_lds16(Ag1 + k0, As1);
    }
    load_lds16(Bg0 + k0, Bs0);
    load_lds16(Bg1 + k0, Bs1);
    if (AF32) {  // vectorized b128 writes, conflict-free [row][32] layout
      *(bf16x8*)&As[(w * 16 + rw) * 32 + c4 * 8] = va0;
      *(bf16x8*)&As[(64 + w * 16 + rw) * 32 + c4 * 8] = va1;
    }
    __syncthreads();  // drains vmcnt (DMA) + lgkm (ds_write) before reads
    bf16x8 a[4], b[4];
#pragma unroll
    for (int mt = 0; mt < 4; ++mt)
      a[mt] = *(const bf16x8*)&As[(wm + mt * 16 + c16) * 32 + quad * 8];
#pragma unroll
    for (int nt = 0; nt < 4; ++nt)
      b[nt] = *(const bf16x8*)&Bs[(wn + nt * 16 + c16) * 32 + quad * 8];
#pragma unroll
    for (int mt = 0; mt < 4; ++mt)
#pragma unroll
      for (int nt = 0; nt < 4; ++nt)
        acc[mt][nt] = __builtin_amdgcn_mfma_f32_16x16x32_bf16(a[mt], b[nt], acc[mt][nt], 0, 0, 0);
    __syncthreads();  // all waves done with tiles before next DMA lands
  }
#pragma unroll
  for (int mt = 0; mt < 4; ++mt)
#pragma unroll
    for (int nt = 0; nt < 4; ++nt)
#pragma unroll
      for (int r = 0; r < 4; ++r) {
        const int row = bm + wm + mt * 16 + quad * 4 + r;
        const int col = bn + wn + nt * 16 + c16;
        const size_t idx = TR ? (size_t)col * ldC + row : (size_t)row * ldC + col;
        if (OF32)
          ((float*)Cv)[idx] = acc[mt][nt][r];
        else
          ((u16*)Cv)[idx] = f2bf(acc[mt][nt][r]);
      }
}

// ---------------------------------------------------------------- RoPE (in place, bf16)
__global__ void rope_kernel(u16* __restrict__ buf, const int* __restrict__ pos,
                            int log2nh, float oscale) {
  const int t = blockIdx.x * 256 + threadIdx.x;
  const int i = t & 63;
  const int h = (t >> 6) & ((1 << log2nh) - 1);
  const int s = t >> (6 + log2nh);
  const int nh = 1 << log2nh;
  const float p = (float)pos[s];
  const float invf = exp2f((float)i * -0.20762051915861040f);  // 10000^(-i/64)
  const float ang = p * invf;
  const float cn = cosf(ang), sn = sinf(ang);
  const size_t i1 = (size_t)s * (nh * 128) + h * 128 + i;
  const size_t i2 = i1 + 64;
  const float x1 = bf2f(buf[i1]), x2 = bf2f(buf[i2]);
  buf[i1] = f2bf((x1 * cn - x2 * sn) * oscale);
  buf[i2] = f2bf((x2 * cn + x1 * sn) * oscale);
}

// ---------------------------------------------------------------- flash attention
// Q: [S,32*128] bf16 (RoPE'd, pre-scaled 1/sqrt(128));  K: [S,8*128] bf16
// VT: [8*128, S] bf16;  O: [S,32*128] bf16.  Block = 64 q-rows x 1 head.
__global__ __launch_bounds__(256) void flash_kernel(const u16* __restrict__ Q,
                                                    const u16* __restrict__ K,
                                                    const u16* __restrict__ VT,
                                                    u16* __restrict__ O) {
  __shared__ __align__(16) u16 Qs[4 * 64 * 32];    // [kc][m][32]
  __shared__ __align__(16) u16 Ks[4 * 64 * 32];    // [kc][key][32]
  __shared__ __align__(16) u16 Vts[2 * 128 * 32];  // [kc2][d][32 keys]
  __shared__ __align__(16) u16 Ps[4][16 * 72];     // per-wave P tile
  const int qb = blockIdx.x, h = blockIdx.y, kvh = h >> 2;
  const int tid = threadIdx.x, lane = tid & 63, w = tid >> 6;
  const int quad = lane >> 4, c16 = lane & 15;
  const int rw = lane >> 2, c4 = lane & 3;

#pragma unroll
  for (int p = 0; p < 4; ++p) {
    bf16x8 v = *(const bf16x8*)&Q[(size_t)(qb * 64 + w * 16 + rw) * 4096 + h * 128 + p * 32 + c4 * 8];
    *(bf16x8*)&Qs[(p * 64 + w * 16 + rw) * 32 + c4 * 8] = v;
  }
  __syncthreads();
  bf16x8 aq[4];
#pragma unroll
  for (int kc = 0; kc < 4; ++kc)
    aq[kc] = *(const bf16x8*)&Qs[(kc * 64 + w * 16 + c16) * 32 + quad * 8];

  f32x4 acc_o[8] = {};
  float m_run[4], l_run[4];
#pragma unroll
  for (int r = 0; r < 4; ++r) { m_run[r] = -1e30f; l_run[r] = 0.f; }

  for (int t = 0; t <= qb; ++t) {
    bf16x8 kv[4], vv[4];
#pragma unroll
    for (int p = 0; p < 4; ++p) {
      kv[p] = *(const bf16x8*)&K[(size_t)(t * 64 + w * 16 + rw) * 1024 + kvh * 128 + p * 32 + c4 * 8];
      const int d = (p & 1) * 64 + w * 16 + rw;
      vv[p] = *(const bf16x8*)&VT[(size_t)(kvh * 128 + d) * 2048 + t * 64 + (p >> 1) * 32 + c4 * 8];
    }
    __syncthreads();
#pragma unroll
    for (int p = 0; p < 4; ++p) {
      *(bf16x8*)&Ks[(p * 64 + w * 16 + rw) * 32 + c4 * 8] = kv[p];
      *(bf16x8*)&Vts[(p * 64 + w * 16 + rw) * 32 + c4 * 8] = vv[p];
    }
    __syncthreads();

    f32x4 sacc[4];
#pragma unroll
    for (int nt = 0; nt < 4; ++nt) {
      f32x4 s = {0.f, 0.f, 0.f, 0.f};
#pragma unroll
      for (int kc = 0; kc < 4; ++kc) {
        bf16x8 bk = *(const bf16x8*)&Ks[(kc * 64 + nt * 16 + c16) * 32 + quad * 8];
        s = __builtin_amdgcn_mfma_f32_16x16x32_bf16(aq[kc], bk, s, 0, 0, 0);
      }
      sacc[nt] = s;
    }
    if (t == qb) {
#pragma unroll
      for (int nt = 0; nt < 4; ++nt)
#pragma unroll
        for (int r = 0; r < 4; ++r)
          if (nt * 16 + c16 > w * 16 + quad * 4 + r) sacc[nt][r] = -1e30f;
    }
    float al[4];
#pragma unroll
    for (int r = 0; r < 4; ++r) {
      float mx = fmaxf(fmaxf(sacc[0][r], sacc[1][r]), fmaxf(sacc[2][r], sacc[3][r]));
#pragma unroll
      for (int off = 1; off < 16; off <<= 1) mx = fmaxf(mx, __shfl_xor(mx, off));
      const float nm = fmaxf(m_run[r], mx);
      al[r] = __expf(m_run[r] - nm);
      m_run[r] = nm;
      float sum = 0.f;
#pragma unroll
      for (int nt = 0; nt < 4; ++nt) {
        const float pv = __expf(sacc[nt][r] - nm);
        sacc[nt][r] = pv;
        sum += pv;
      }
#pragma unroll
      for (int off = 1; off < 16; off <<= 1) sum += __shfl_xor(sum, off);
      l_run[r] = l_run[r] * al[r] + sum;
    }
#pragma unroll
    for (int dt = 0; dt < 8; ++dt)
#pragma unroll
      for (int r = 0; r < 4; ++r) acc_o[dt][r] *= al[r];
#pragma unroll
    for (int nt = 0; nt < 4; ++nt)
#pragma unroll
      for (int r = 0; r < 4; ++r)
        Ps[w][(quad * 4 + r) * 72 + nt * 16 + c16] = f2bf(sacc[nt][r]);
    asm volatile("s_waitcnt lgkmcnt(0)" ::: "memory");
    bf16x8 ap[2];
#pragma unroll
    for (int kc = 0; kc < 2; ++kc)
      ap[kc] = *(const bf16x8*)&Ps[w][c16 * 72 + kc * 32 + quad * 8];
#pragma unroll
    for (int dt = 0; dt < 8; ++dt)
#pragma unroll
      for (int kc = 0; kc < 2; ++kc) {
        bf16x8 bv = *(const bf16x8*)&Vts[(kc * 128 + dt * 16 + c16) * 32 + quad * 8];
        acc_o[dt] = __builtin_amdgcn_mfma_f32_16x16x32_bf16(ap[kc], bv, acc_o[dt], 0, 0, 0);
      }
  }
#pragma unroll
  for (int r = 0; r < 4; ++r) {
    const float inv = 1.0f / l_run[r];
    const int row = qb * 64 + w * 16 + quad * 4 + r;
#pragma unroll
    for (int dt = 0; dt < 8; ++dt)
      O[(size_t)row * 4096 + h * 128 + dt * 16 + c16] = f2bf(acc_o[dt][r] * inv);
  }
}

// ---------------------------------------------------------------- launch
extern "C" void kernel_launch(void* const* d_in, const int* in_sizes, int n_in,
                              void* d_out, int out_size, void* d_ws, size_t ws_size,
                              hipStream_t stream) {
  const float* X  = (const float*)d_in[0];   // [2048,4096] f32
  const int* pos  = (const int*)d_in[2];     // causal mask (d_in[1]) applied analytically
  const float* Wq = (const float*)d_in[3];   // [4096,4096] f32
  const float* Wk = (const float*)d_in[4];   // [4096,1024] f32
  const float* Wv = (const float*)d_in[5];   // [4096,1024] f32
  const float* Wo = (const float*)d_in[6];   // [4096,4096] f32
  float* out = (float*)d_out;                // [2048,4096] f32

  // ws_size is fixed per session -> branch is deterministic (graph-safe).
  // big: WT 32MB @0, Att 16MB @32M (48MB).  small: WT 16MB @0, Att @16M (32MB).
  const int NP = (ws_size >= (size_t)50331648) ? 4096 : 2048;  // weight-panel width
  char* ws = (char*)d_ws;
  u16* WT  = (u16*)ws;
  u16* Att = (u16*)(ws + (NP == 4096 ? 33554432 : 16777216));
  // d_out hosts bf16 intermediates until gemmO overwrites it (stream-ordered):
  u16* Qb  = (u16*)d_out;                    // 16 MB  (rows 0..1023 of f32 out)
  u16* Kb  = (u16*)((char*)d_out + 16777216);  // 4 MB
  u16* VTb = (u16*)((char*)d_out + 20971520);  // 4 MB (V^T [1024][2048])

  const dim3 b256(256);

  // Q projection (panelled over N)
  for (int p = 0; p < 4096; p += NP) {
    transpose_w<<<dim3(NP / 32, 128), b256, 0, stream>>>(Wq, WT, 4096, 4096, p);
    gemm_bt<1, 0, 0><<<dim3(16, NP / 128), b256, 0, stream>>>(X, WT, Qb + p, 2048, NP, 4096, 4096);
  }
  // K projection
  transpose_w<<<dim3(32, 128), b256, 0, stream>>>(Wk, WT, 4096, 1024, 0);
  gemm_bt<1, 0, 0><<<dim3(16, 8), b256, 0, stream>>>(X, WT, Kb, 2048, 1024, 4096, 1024);
  // V projection, output transposed -> VTb [1024][2048]
  transpose_w<<<dim3(32, 128), b256, 0, stream>>>(Wv, WT, 4096, 1024, 0);
  gemm_bt<1, 0, 1><<<dim3(16, 8), b256, 0, stream>>>(X, WT, VTb, 2048, 1024, 4096, 2048);

  // RoPE (Q pre-scaled by 1/sqrt(128))
  rope_kernel<<<dim3(2048 * 32 * 64 / 256), b256, 0, stream>>>(Qb, pos, 5, 0.08838834764831845f);
  rope_kernel<<<dim3(2048 * 8 * 64 / 256),  b256, 0, stream>>>(Kb, pos, 3, 1.0f);

  flash_kernel<<<dim3(32, 32), b256, 0, stream>>>(Qb, Kb, VTb, Att);

  // O projection (reads Att bf16 + WT panels, writes f32 out; Qb/Kb/VTb dead)
  for (int p = 0; p < 4096; p += NP) {
    transpose_w<<<dim3(NP / 32, 128), b256, 0, stream>>>(Wo, WT, 4096, 4096, p);
    gemm_bt<0, 1, 0><<<dim3(16, NP / 128), b256, 0, stream>>>(Att, WT, out + p, 2048, NP, 4096, 4096);
  }
}